// Round 2
// baseline (410.160 us; speedup 1.0000x reference)
//
#include <hip/hip_runtime.h>
#include <math.h>

#define N_NODES 50000
#define N_EDGES 600000

constexpr float RS          = 1.6765324703310907f;
constexpr float INV_SQRT8   = 0.35355339059327373f;
constexpr float INV8        = 0.125f;
constexpr float INV_SQRT320 = 0.05590169943749474f;
constexpr float INV_SQRT32  = 0.17677669529663687f;
constexpr float INV_SQRT96  = 0.10206207261596575f;
constexpr float INV_AVG     = 1.0f / 12.0f;

// ws layout (bytes)
constexpr size_t OFF_X     = 0;           // N*32 float4 = 25,600,000
constexpr size_t OFF_ROW   = 25600000;    // (N+1) int   =    200,004
constexpr size_t OFF_FRAG  = 25800064;    // 40 frag-sets * 512 bf16 = 40,960
constexpr size_t OFF_FRAG2 = 25841024;    // 88 frag-sets * 512 bf16 = 90,112
constexpr size_t OFF_W     = 25931136;    // E*160 bf16  = 192,000,000

typedef __attribute__((ext_vector_type(8))) short bfrag;   // 8 bf16 (4 VGPRs)
typedef __attribute__((ext_vector_type(4))) float ffrag;   // 4 fp32 acc

__device__ __forceinline__ float rsilu(float z) {
  return RS * z / (1.0f + __expf(-z));
}
__device__ __forceinline__ unsigned short f2bf(float x) {
  unsigned u = __float_as_uint(x);
  u += 0x7FFFu + ((u >> 16) & 1u);
  return (unsigned short)(u >> 16);
}
__device__ __forceinline__ float bf2f(unsigned short u) {
  return __uint_as_float(((unsigned)u) << 16);
}

// ---------------- CSR row offsets from sorted idx_i ----------------
__global__ __launch_bounds__(256) void k_rowstart(const int* __restrict__ idx_i,
                                                  int* __restrict__ row,
                                                  int E, int N) {
  int e = blockIdx.x * 256 + threadIdx.x;
  if (e >= E) return;
  int cur  = idx_i[e];
  int prev = (e == 0) ? -1 : idx_i[e - 1];
  for (int n = prev + 1; n <= cur; ++n) row[n] = e;
  if (e == E - 1) {
    for (int n = cur + 1; n <= N; ++n) row[n] = E;
  }
}

// ---------------- pre-pack MLP weights into MFMA B-fragment order ----------
__global__ __launch_bounds__(256) void k_prep(const float* __restrict__ Wr0,
                                              const float* __restrict__ Wr1,
                                              const float* __restrict__ Wr2,
                                              const float* __restrict__ Wr3,
                                              unsigned short* __restrict__ frag) {
  int t = blockIdx.x * 256 + threadIdx.x;   // exactly 40*512 = 20480 threads
  int f    = t >> 9;
  int lane = (t >> 3) & 63;
  int j    = t & 7;
  int n16  = lane & 15, quad = lane >> 4;
  float v;
  if (f < 4) {
    int d = f * 16 + n16, k = quad * 8 + j;
    v = (k < 8) ? Wr0[d * 8 + k] : 0.f;
  } else if (f < 12) {
    int ff = f - 4, ntile = ff >> 1, ks = ff & 1;
    int d = ntile * 16 + n16, k = ks * 32 + quad * 8 + j;
    v = Wr1[d * 64 + k];
  } else if (f < 20) {
    int ff = f - 12, ntile = ff >> 1, ks = ff & 1;
    int d = ntile * 16 + n16, k = ks * 32 + quad * 8 + j;
    v = Wr2[d * 64 + k];
  } else {
    int ff = f - 20, ntile = ff >> 1, ks = ff & 1;
    int d = ntile * 16 + n16, k = ks * 32 + quad * 8 + j;
    v = Wr3[d * 64 + k];
  }
  frag[t] = f2bf(v);
}

// ---------------- pre-pack node weights: B2 [K=352][128 cols], frag order ---
__global__ __launch_bounds__(256) void k_prep2(const float* __restrict__ Wsk,
                                               const float* __restrict__ Wf,
                                               unsigned short* __restrict__ frag2) {
  int t = blockIdx.x * 256 + threadIdx.x;   // exactly 88*512 = 45056 threads
  int f    = t >> 9;
  int lane = (t >> 3) & 63;
  int j    = t & 7;
  int n16  = lane & 15, quad = lane >> 4;
  int ks = f >> 3, nt = f & 7;
  int k   = ks * 32 + quad * 8 + j;
  int col = nt * 16 + n16;
  float v = 0.f;
  if (k < 320) {
    int vv = k >> 5, c = k & 31;
    if (col < 32)       v = Wsk[(c * 10 + vv) * 32 + col] * INV_SQRT320;
    else if (col < 64)  v = Wsk[((32 + c) * 10 + vv) * 32 + (col - 32)] * INV_SQRT320;
  } else {
    int c = k - 320;
    if (col >= 96)      v = Wf[1024 + (col - 96) * 32 + c] * INV_SQRT32;
    else if (col >= 64) v = Wf[(col - 64) * 32 + c] * INV_SQRT32;
  }
  frag2[t] = f2bf(v);
}

// ---------------- per-node sc + x via MFMA ----------------
__global__ __launch_bounds__(256) void k_node_mfma(const float* __restrict__ attrs,
                                                   const float* __restrict__ feats,
                                                   const unsigned short* __restrict__ frag2,
                                                   float* __restrict__ out_sc,
                                                   float* __restrict__ x_ws) {
  int tid = threadIdx.x;
  int wave = tid >> 6, lane = tid & 63;
  int quad = lane >> 4, l16 = lane & 15;
  int nb = blockIdx.x * 32 + wave * 8;

  float featsF[2][8];
  float a[2][10];
#pragma unroll
  for (int mt = 0; mt < 2; ++mt) {
    int nodeA = nb + mt * 4 + (l16 >> 2);
    if (nodeA > N_NODES - 1) nodeA = N_NODES - 1;
    int m = l16 & 3;
#pragma unroll
    for (int j = 0; j < 8; ++j)
      featsF[mt][j] = feats[(size_t)nodeA * 128 + (quad * 8 + j) * 4 + m];
#pragma unroll
    for (int v = 0; v < 10; ++v) a[mt][v] = attrs[nodeA * 10 + v];
  }

  ffrag acc[2][8];
#pragma unroll
  for (int mt = 0; mt < 2; ++mt)
#pragma unroll
    for (int nt = 0; nt < 8; ++nt) acc[mt][nt] = (ffrag){0.f, 0.f, 0.f, 0.f};

#pragma unroll
  for (int ks = 0; ks < 11; ++ks) {
    bfrag Ab[2];
#pragma unroll
    for (int mt = 0; mt < 2; ++mt) {
      union { unsigned short s8[8]; bfrag v; } pk;
#pragma unroll
      for (int j = 0; j < 8; ++j) {
        float val = (ks < 10) ? a[mt][ks] * featsF[mt][j] : featsF[mt][j];
        pk.s8[j] = f2bf(val);
      }
      Ab[mt] = pk.v;
    }
#pragma unroll
    for (int nt = 0; nt < 8; ++nt) {
      bfrag B = *(const bfrag*)(frag2 + ((size_t)(ks * 8 + nt) * 64 + lane) * 8);
      acc[0][nt] = __builtin_amdgcn_mfma_f32_16x16x32_bf16(Ab[0], B, acc[0][nt], 0, 0, 0);
      acc[1][nt] = __builtin_amdgcn_mfma_f32_16x16x32_bf16(Ab[1], B, acc[1][nt], 0, 0, 0);
    }
  }

#pragma unroll
  for (int mt = 0; mt < 2; ++mt) {
    int node = nb + mt * 4 + quad;
    if (node < N_NODES) {
      float4 sc0 = {acc[mt][0][0], acc[mt][2][1], acc[mt][2][2], acc[mt][2][3]};
      float4 sc1 = {acc[mt][1][0], acc[mt][3][1], acc[mt][3][2], acc[mt][3][3]};
      float4 x0  = {acc[mt][4][0], acc[mt][6][1], acc[mt][6][2], acc[mt][6][3]};
      float4 x1  = {acc[mt][5][0], acc[mt][7][1], acc[mt][7][2], acc[mt][7][3]};
      ((float4*)out_sc)[(size_t)node * 32 + l16]      = sc0;
      ((float4*)out_sc)[(size_t)node * 32 + 16 + l16] = sc1;
      ((float4*)x_ws)[(size_t)node * 32 + l16]        = x0;
      ((float4*)x_ws)[(size_t)node * 32 + 16 + l16]   = x1;
    }
  }
}

// ---------------- per-edge 4-layer MLP via MFMA -> w (bf16, E x 160) -------
// v3: layer-4 output stored in PAIR-PACKED order per edge row:
//   bf16 idx 2c+0 = w[p=0][c], 2c+1 = w[p=1][c]      (dword pair {w0,w1})
//   64 + 2c+0 = w[p=2][c], 64+2c+1 = w[p=3][c]       (dword pair {w2,w3})
//   128 + c   = w[p=4][c]
// so k_msg reads 3 loads/edge instead of 5. Flush logic unchanged.
#define MLP_M 128
__global__ __launch_bounds__(256) void k_mlp(const float* __restrict__ ef,
                                             const unsigned short* __restrict__ frag,
                                             unsigned short* __restrict__ w_out,
                                             int E) {
  __shared__ __align__(16) unsigned short H[4][32][168];
  int tid = threadIdx.x;
  int wave = tid >> 6, lane = tid & 63;
  int quad = lane >> 4, l16 = lane & 15;
  int m0 = blockIdx.x * MLP_M + wave * 32;   // wave's first edge row
  unsigned short (*Hw)[168] = H[wave];

  // ---- layer 1: A = edge_feats rows (K=8 zero-padded to 32) ----
  bfrag a1[2];
#pragma unroll
  for (int mt = 0; mt < 2; ++mt) {
    float vals[8] = {0.f, 0.f, 0.f, 0.f, 0.f, 0.f, 0.f, 0.f};
    if (quad == 0) {
      int r = m0 + mt * 16 + l16;
      if (r > E - 1) r = E - 1;
      const float4* p = (const float4*)(ef + (size_t)r * 8);
      float4 u0 = p[0], u1 = p[1];
      vals[0] = u0.x; vals[1] = u0.y; vals[2] = u0.z; vals[3] = u0.w;
      vals[4] = u1.x; vals[5] = u1.y; vals[6] = u1.z; vals[7] = u1.w;
    }
    union { unsigned short s[8]; bfrag v; } pk;
#pragma unroll
    for (int j = 0; j < 8; ++j) pk.s[j] = f2bf(vals[j]);
    a1[mt] = pk.v;
  }
#pragma unroll
  for (int nt = 0; nt < 4; ++nt) {
    const bfrag* bp = (const bfrag*)(frag + ((size_t)(nt) * 64 + lane) * 8);
    bfrag b = *bp;
    ffrag acc0 = {0.f, 0.f, 0.f, 0.f}, acc1 = acc0;
    acc0 = __builtin_amdgcn_mfma_f32_16x16x32_bf16(a1[0], b, acc0, 0, 0, 0);
    acc1 = __builtin_amdgcn_mfma_f32_16x16x32_bf16(a1[1], b, acc1, 0, 0, 0);
#pragma unroll
    for (int r = 0; r < 4; ++r) {
      Hw[0 * 16 + quad * 4 + r][nt * 16 + l16] = f2bf(rsilu(acc0[r] * INV_SQRT8));
      Hw[1 * 16 + quad * 4 + r][nt * 16 + l16] = f2bf(rsilu(acc1[r] * INV_SQRT8));
    }
  }

  // ---- layers 2,3 (N=64) ----
  bfrag A[2][2];
#pragma unroll 1
  for (int L = 0; L < 2; ++L) {           // layers 2 and 3
    int fbase = 4 + L * 8;
#pragma unroll
    for (int mt = 0; mt < 2; ++mt)
#pragma unroll
      for (int ks = 0; ks < 2; ++ks)
        A[mt][ks] = *(const bfrag*)&Hw[mt * 16 + l16][ks * 32 + quad * 8];
#pragma unroll
    for (int nt = 0; nt < 4; ++nt) {
      ffrag acc0 = {0.f, 0.f, 0.f, 0.f}, acc1 = acc0;
#pragma unroll
      for (int ks = 0; ks < 2; ++ks) {
        bfrag b = *(const bfrag*)(frag + ((size_t)(fbase + nt * 2 + ks) * 64 + lane) * 8);
        acc0 = __builtin_amdgcn_mfma_f32_16x16x32_bf16(A[0][ks], b, acc0, 0, 0, 0);
        acc1 = __builtin_amdgcn_mfma_f32_16x16x32_bf16(A[1][ks], b, acc1, 0, 0, 0);
      }
#pragma unroll
      for (int r = 0; r < 4; ++r) {
        Hw[0 * 16 + quad * 4 + r][nt * 16 + l16] = f2bf(rsilu(acc0[r] * INV8));
        Hw[1 * 16 + quad * 4 + r][nt * 16 + l16] = f2bf(rsilu(acc1[r] * INV8));
      }
    }
  }

  // layer 4: w = h3 @ Wr3^T / 8, no activation; stage bf16 rows in LDS
  // (pair-packed column permutation, see header comment)
#pragma unroll
  for (int mt = 0; mt < 2; ++mt)
#pragma unroll
    for (int ks = 0; ks < 2; ++ks)
      A[mt][ks] = *(const bfrag*)&Hw[mt * 16 + l16][ks * 32 + quad * 8];
#pragma unroll 2
  for (int nt = 0; nt < 10; ++nt) {
    ffrag acc0 = {0.f, 0.f, 0.f, 0.f}, acc1 = acc0;
#pragma unroll
    for (int ks = 0; ks < 2; ++ks) {
      bfrag b = *(const bfrag*)(frag + ((size_t)(20 + nt * 2 + ks) * 64 + lane) * 8);
      acc0 = __builtin_amdgcn_mfma_f32_16x16x32_bf16(A[0][ks], b, acc0, 0, 0, 0);
      acc1 = __builtin_amdgcn_mfma_f32_16x16x32_bf16(A[1][ks], b, acc1, 0, 0, 0);
    }
    int col = nt * 16 + l16;
    int p = col >> 5, cc = col & 31;
    int ncol = (p < 4) ? ((p >> 1) * 64 + 2 * cc + (p & 1)) : (128 + cc);
#pragma unroll
    for (int r = 0; r < 4; ++r) {
      Hw[0 * 16 + quad * 4 + r][ncol] = f2bf(acc0[r] * INV8);
      Hw[1 * 16 + quad * 4 + r][ncol] = f2bf(acc1[r] * INV8);
    }
  }

  // flush: 32 rows x 160 bf16 -> global, 16 B chunks
#pragma unroll 2
  for (int it = 0; it < 10; ++it) {
    int c = it * 64 + lane;            // 0..639
    int row = c / 20, off = c % 20;
    int grow = m0 + row;
    uint4 v = *(const uint4*)&Hw[row][off * 8];
    if (grow < E)
      *(uint4*)(w_out + (size_t)grow * 160 + off * 8) = v;
  }
}

// ---------------- per-node message accumulation + W_second contraction ----------------
// v3:
//  - w reads: 3 loads/edge (2 bf16-pair dwords + 1 ushort); unpack via shift/AND.
//  - batch depth 8 (~40 loads in flight per 32-lane group).
//  - msg LDS row re-laid out as [m0(64)][m1 m=0 (96)][m=1 (96)][m=2 (96)],
//    stride 356 (16B aligned) -> tail msg reads become broadcast ds_read_b128.
__global__ __launch_bounds__(256, 4) void k_msg(const unsigned short* __restrict__ w_ws,
                                                const float* __restrict__ x_ws,
                                                const float* __restrict__ ea,
                                                const int* __restrict__ idx_j,
                                                const int* __restrict__ row,
                                                const float* __restrict__ Ws0,
                                                const float* __restrict__ Ws1,
                                                float* __restrict__ out_msg) {
  __shared__ __align__(16) float msg[8][356];  // 352 comps, stride 356 (16B-aligned)
  __shared__ float W0T[64 * 33];    // [k*33+d]
  __shared__ float W1T[96 * 33];

  int tid = threadIdx.x;
  for (int t = tid; t < 2048; t += 256) {     // Ws0 (32x64) -> W0T[k][d]
    int d = t >> 6, k = t & 63;
    W0T[k * 33 + d] = Ws0[t];
  }
  for (int t = tid; t < 3072; t += 256) {     // Ws1 (32x96) -> W1T[k][d]
    int d = t / 96, k = t % 96;
    W1T[k * 33 + d] = Ws1[t];
  }

  int ln = tid >> 5, c = tid & 31;
  int n = blockIdx.x * 8 + ln;                // grid exactly N/8
  int e0 = row[n], e1 = row[n + 1];

  float m00 = 0.f, m01 = 0.f;
  float m10x = 0.f, m10y = 0.f, m10z = 0.f;
  float m11x = 0.f, m11y = 0.f, m11z = 0.f;
  float m12x = 0.f, m12y = 0.f, m12z = 0.f;

  for (int base = e0; base < e1; base += 32) {
    int rem = e1 - base;
    int cnt = rem < 32 ? rem : 32;
    // one coalesced load covers this chunk's indices (dup-clamped for c>=cnt)
    int jidx = base + (c < cnt ? c : cnt - 1);
    int j_c = __builtin_nontemporal_load(idx_j + jidx);

    for (int b = 0; b < cnt; b += 8) {
      int mvalid = cnt - b;                   // >= 1
      float4 xj[8], y4[8];
      unsigned d01[8], d23[8];
      unsigned short w4v[8];
#pragma unroll
      for (int t = 0; t < 8; ++t) {
        int tt = (t < mvalid) ? t : 0;        // clamp to a valid edge (loads safe)
        int e = base + b + tt;
        int j = __shfl(j_c, b + tt, 32);
        xj[t] = ((const float4*)x_ws)[(size_t)j * 32 + c];
        y4[t] = ((const float4*)ea)[e];
        const char* wb = (const char*)w_ws + (size_t)e * 320;
        d01[t] = *(const unsigned*)(wb + 4 * c);
        d23[t] = *(const unsigned*)(wb + 128 + 4 * c);
        w4v[t] = *(const unsigned short*)(wb + 256 + 2 * c);
      }
#pragma unroll
      for (int t = 0; t < 8; ++t) {
        if (t < mvalid) {
          float w0 = __uint_as_float(d01[t] << 16);
          float w1 = __uint_as_float(d01[t] & 0xffff0000u);
          float w2 = __uint_as_float(d23[t] << 16);
          float w3 = __uint_as_float(d23[t] & 0xffff0000u);
          float w4 = bf2f(w4v[t]);
          float4 x4 = xj[t], yy = y4[t];
          m00 += w0 * x4.x * yy.x;                                      // p0
          m01 += w3 * (x4.y * yy.y + x4.z * yy.z + x4.w * yy.w);        // p3
          m10x += w1 * x4.x * yy.y;
          m10y += w1 * x4.x * yy.z;
          m10z += w1 * x4.x * yy.w;                                     // p1
          m11x += w2 * x4.y * yy.x;
          m11y += w2 * x4.z * yy.x;
          m11z += w2 * x4.w * yy.x;                                     // p2
          float cx = x4.z * yy.w - x4.w * yy.z;
          float cy = x4.w * yy.y - x4.y * yy.w;
          float cz = x4.y * yy.z - x4.z * yy.y;
          m12x += w4 * cx;
          m12y += w4 * cy;
          m12z += w4 * cz;                                              // p4
        }
      }
    }
  }

  // msg row layout: [0..63] = {m00, m01}; [64 + m*96 + p'*32 + c], p' in {p1,p2,p4}
  msg[ln][c]      = m00;
  msg[ln][32 + c] = m01;
  msg[ln][64 + 0 * 96 +  0 + c] = m10x;
  msg[ln][64 + 0 * 96 + 32 + c] = m11x;
  msg[ln][64 + 0 * 96 + 64 + c] = m12x;
  msg[ln][64 + 1 * 96 +  0 + c] = m10y;
  msg[ln][64 + 1 * 96 + 32 + c] = m11y;
  msg[ln][64 + 1 * 96 + 64 + c] = m12y;
  msg[ln][64 + 2 * 96 +  0 + c] = m10z;
  msg[ln][64 + 2 * 96 + 32 + c] = m11z;
  msg[ln][64 + 2 * 96 + 64 + c] = m12z;
  __syncthreads();

  // out0[n][d=c] via float4 msg reads (broadcast b128)
  float o0 = 0.f;
#pragma unroll 4
  for (int k4 = 0; k4 < 16; ++k4) {
    float4 mk = *(const float4*)&msg[ln][4 * k4];
    o0 += mk.x * W0T[(4 * k4 + 0) * 33 + c];
    o0 += mk.y * W0T[(4 * k4 + 1) * 33 + c];
    o0 += mk.z * W0T[(4 * k4 + 2) * 33 + c];
    o0 += mk.w * W0T[(4 * k4 + 3) * 33 + c];
  }
  // out1[n][d=c][m]
  float o1x = 0.f, o1y = 0.f, o1z = 0.f;
#pragma unroll 4
  for (int k4 = 0; k4 < 24; ++k4) {
    float4 ax = *(const float4*)&msg[ln][64 + 0 * 96 + 4 * k4];
    float4 ay = *(const float4*)&msg[ln][64 + 1 * 96 + 4 * k4];
    float4 az = *(const float4*)&msg[ln][64 + 2 * 96 + 4 * k4];
#pragma unroll
    for (int i = 0; i < 4; ++i) {
      float wv = W1T[(4 * k4 + i) * 33 + c];
      float mx = (i == 0) ? ax.x : (i == 1) ? ax.y : (i == 2) ? ax.z : ax.w;
      float my = (i == 0) ? ay.x : (i == 1) ? ay.y : (i == 2) ? ay.z : ay.w;
      float mz = (i == 0) ? az.x : (i == 1) ? az.y : (i == 2) ? az.z : az.w;
      o1x += mx * wv;
      o1y += my * wv;
      o1z += mz * wv;
    }
  }
  float4 res = {o0 * INV8 * INV_AVG, o1x * INV_SQRT96 * INV_AVG,
                o1y * INV_SQRT96 * INV_AVG, o1z * INV_SQRT96 * INV_AVG};
  ((float4*)out_msg)[(size_t)n * 32 + c] = res;
}

extern "C" void kernel_launch(void* const* d_in, const int* in_sizes, int n_in,
                              void* d_out, int out_size, void* d_ws, size_t ws_size,
                              hipStream_t stream) {
  const float* node_attrs = (const float*)d_in[0];
  const float* node_feats = (const float*)d_in[1];
  const float* edge_attrs = (const float*)d_in[2];
  const float* edge_feats = (const float*)d_in[3];
  const float* W_first    = (const float*)d_in[4];
  const float* Wr0        = (const float*)d_in[5];
  const float* Wr1        = (const float*)d_in[6];
  const float* Wr2        = (const float*)d_in[7];
  const float* Wr3        = (const float*)d_in[8];
  const float* Ws0        = (const float*)d_in[9];
  const float* Ws1        = (const float*)d_in[10];
  const float* Wsk        = (const float*)d_in[11];
  const int*   idx_i      = (const int*)d_in[12];
  const int*   idx_j      = (const int*)d_in[13];
  float* out = (float*)d_out;

  char* ws = (char*)d_ws;
  float*          x_ws   = (float*)(ws + OFF_X);
  int*            rowp   = (int*)(ws + OFF_ROW);
  unsigned short* fragp  = (unsigned short*)(ws + OFF_FRAG);
  unsigned short* frag2p = (unsigned short*)(ws + OFF_FRAG2);
  unsigned short* w_ws   = (unsigned short*)(ws + OFF_W);

  k_rowstart<<<(N_EDGES + 255) / 256, 256, 0, stream>>>(idx_i, rowp, N_EDGES, N_NODES);
  k_prep<<<80, 256, 0, stream>>>(Wr0, Wr1, Wr2, Wr3, fragp);
  k_prep2<<<176, 256, 0, stream>>>(Wsk, W_first, frag2p);
  k_node_mfma<<<(N_NODES + 31) / 32, 256, 0, stream>>>(node_attrs, node_feats,
                                                       frag2p, out + 6400000, x_ws);
  k_mlp<<<(N_EDGES + MLP_M - 1) / MLP_M, 256, 0, stream>>>(edge_feats, fragp,
                                                           w_ws, N_EDGES);
  k_msg<<<N_NODES / 8, 256, 0, stream>>>(w_ws, x_ws, edge_attrs, idx_j, rowp,
                                         Ws0, Ws1, out);
}

// Round 3
// 370.305 us; speedup vs baseline: 1.1076x; 1.1076x over previous
//
#include <hip/hip_runtime.h>
#include <math.h>

#define N_NODES 50000
#define N_EDGES 600000

constexpr float RS          = 1.6765324703310907f;
constexpr float INV_SQRT8   = 0.35355339059327373f;
constexpr float INV8        = 0.125f;
constexpr float INV_SQRT320 = 0.05590169943749474f;
constexpr float INV_SQRT32  = 0.17677669529663687f;
constexpr float INV_SQRT96  = 0.10206207261596575f;
constexpr float INV_AVG     = 1.0f / 12.0f;

// ws layout (bytes)
constexpr size_t OFF_X     = 0;           // N*32 float4 = 25,600,000
constexpr size_t OFF_ROW   = 25600000;    // (N+1) int   =    200,004
constexpr size_t OFF_FRAG  = 25800064;    // 40 frag-sets * 512 bf16 = 40,960
constexpr size_t OFF_FRAG2 = 25841024;    // 88 frag-sets * 512 bf16 = 90,112
constexpr size_t OFF_W     = 25931136;    // E*160 bf16  = 192,000,000

typedef __attribute__((ext_vector_type(8))) short bfrag;   // 8 bf16 (4 VGPRs)
typedef __attribute__((ext_vector_type(4))) float ffrag;   // 4 fp32 acc

__device__ __forceinline__ float rsilu(float z) {
  return RS * z / (1.0f + __expf(-z));
}
__device__ __forceinline__ unsigned short f2bf(float x) {
  unsigned u = __float_as_uint(x);
  u += 0x7FFFu + ((u >> 16) & 1u);
  return (unsigned short)(u >> 16);
}
__device__ __forceinline__ float bf2f(unsigned short u) {
  return __uint_as_float(((unsigned)u) << 16);
}

// ---------------- CSR row offsets from sorted idx_i ----------------
__global__ __launch_bounds__(256) void k_rowstart(const int* __restrict__ idx_i,
                                                  int* __restrict__ row,
                                                  int E, int N) {
  int e = blockIdx.x * 256 + threadIdx.x;
  if (e >= E) return;
  int cur  = idx_i[e];
  int prev = (e == 0) ? -1 : idx_i[e - 1];
  for (int n = prev + 1; n <= cur; ++n) row[n] = e;
  if (e == E - 1) {
    for (int n = cur + 1; n <= N; ++n) row[n] = E;
  }
}

// ---------------- pre-pack MLP weights into MFMA B-fragment order ----------
__global__ __launch_bounds__(256) void k_prep(const float* __restrict__ Wr0,
                                              const float* __restrict__ Wr1,
                                              const float* __restrict__ Wr2,
                                              const float* __restrict__ Wr3,
                                              unsigned short* __restrict__ frag) {
  int t = blockIdx.x * 256 + threadIdx.x;   // exactly 40*512 = 20480 threads
  int f    = t >> 9;
  int lane = (t >> 3) & 63;
  int j    = t & 7;
  int n16  = lane & 15, quad = lane >> 4;
  float v;
  if (f < 4) {
    int d = f * 16 + n16, k = quad * 8 + j;
    v = (k < 8) ? Wr0[d * 8 + k] : 0.f;
  } else if (f < 12) {
    int ff = f - 4, ntile = ff >> 1, ks = ff & 1;
    int d = ntile * 16 + n16, k = ks * 32 + quad * 8 + j;
    v = Wr1[d * 64 + k];
  } else if (f < 20) {
    int ff = f - 12, ntile = ff >> 1, ks = ff & 1;
    int d = ntile * 16 + n16, k = ks * 32 + quad * 8 + j;
    v = Wr2[d * 64 + k];
  } else {
    int ff = f - 20, ntile = ff >> 1, ks = ff & 1;
    int d = ntile * 16 + n16, k = ks * 32 + quad * 8 + j;
    v = Wr3[d * 64 + k];
  }
  frag[t] = f2bf(v);
}

// ---------------- pre-pack node weights: B2 [K=352][128 cols], frag order ---
__global__ __launch_bounds__(256) void k_prep2(const float* __restrict__ Wsk,
                                               const float* __restrict__ Wf,
                                               unsigned short* __restrict__ frag2) {
  int t = blockIdx.x * 256 + threadIdx.x;   // exactly 88*512 = 45056 threads
  int f    = t >> 9;
  int lane = (t >> 3) & 63;
  int j    = t & 7;
  int n16  = lane & 15, quad = lane >> 4;
  int ks = f >> 3, nt = f & 7;
  int k   = ks * 32 + quad * 8 + j;
  int col = nt * 16 + n16;
  float v = 0.f;
  if (k < 320) {
    int vv = k >> 5, c = k & 31;
    if (col < 32)       v = Wsk[(c * 10 + vv) * 32 + col] * INV_SQRT320;
    else if (col < 64)  v = Wsk[((32 + c) * 10 + vv) * 32 + (col - 32)] * INV_SQRT320;
  } else {
    int c = k - 320;
    if (col >= 96)      v = Wf[1024 + (col - 96) * 32 + c] * INV_SQRT32;
    else if (col >= 64) v = Wf[(col - 64) * 32 + c] * INV_SQRT32;
  }
  frag2[t] = f2bf(v);
}

// ---------------- per-node sc + x via MFMA ----------------
__global__ __launch_bounds__(256) void k_node_mfma(const float* __restrict__ attrs,
                                                   const float* __restrict__ feats,
                                                   const unsigned short* __restrict__ frag2,
                                                   float* __restrict__ out_sc,
                                                   float* __restrict__ x_ws) {
  int tid = threadIdx.x;
  int wave = tid >> 6, lane = tid & 63;
  int quad = lane >> 4, l16 = lane & 15;
  int nb = blockIdx.x * 32 + wave * 8;

  float featsF[2][8];
  float a[2][10];
#pragma unroll
  for (int mt = 0; mt < 2; ++mt) {
    int nodeA = nb + mt * 4 + (l16 >> 2);
    if (nodeA > N_NODES - 1) nodeA = N_NODES - 1;
    int m = l16 & 3;
#pragma unroll
    for (int j = 0; j < 8; ++j)
      featsF[mt][j] = feats[(size_t)nodeA * 128 + (quad * 8 + j) * 4 + m];
#pragma unroll
    for (int v = 0; v < 10; ++v) a[mt][v] = attrs[nodeA * 10 + v];
  }

  ffrag acc[2][8];
#pragma unroll
  for (int mt = 0; mt < 2; ++mt)
#pragma unroll
    for (int nt = 0; nt < 8; ++nt) acc[mt][nt] = (ffrag){0.f, 0.f, 0.f, 0.f};

#pragma unroll
  for (int ks = 0; ks < 11; ++ks) {
    bfrag Ab[2];
#pragma unroll
    for (int mt = 0; mt < 2; ++mt) {
      union { unsigned short s8[8]; bfrag v; } pk;
#pragma unroll
      for (int j = 0; j < 8; ++j) {
        float val = (ks < 10) ? a[mt][ks] * featsF[mt][j] : featsF[mt][j];
        pk.s8[j] = f2bf(val);
      }
      Ab[mt] = pk.v;
    }
#pragma unroll
    for (int nt = 0; nt < 8; ++nt) {
      bfrag B = *(const bfrag*)(frag2 + ((size_t)(ks * 8 + nt) * 64 + lane) * 8);
      acc[0][nt] = __builtin_amdgcn_mfma_f32_16x16x32_bf16(Ab[0], B, acc[0][nt], 0, 0, 0);
      acc[1][nt] = __builtin_amdgcn_mfma_f32_16x16x32_bf16(Ab[1], B, acc[1][nt], 0, 0, 0);
    }
  }

#pragma unroll
  for (int mt = 0; mt < 2; ++mt) {
    int node = nb + mt * 4 + quad;
    if (node < N_NODES) {
      float4 sc0 = {acc[mt][0][0], acc[mt][2][1], acc[mt][2][2], acc[mt][2][3]};
      float4 sc1 = {acc[mt][1][0], acc[mt][3][1], acc[mt][3][2], acc[mt][3][3]};
      float4 x0  = {acc[mt][4][0], acc[mt][6][1], acc[mt][6][2], acc[mt][6][3]};
      float4 x1  = {acc[mt][5][0], acc[mt][7][1], acc[mt][7][2], acc[mt][7][3]};
      ((float4*)out_sc)[(size_t)node * 32 + l16]      = sc0;
      ((float4*)out_sc)[(size_t)node * 32 + 16 + l16] = sc1;
      ((float4*)x_ws)[(size_t)node * 32 + l16]        = x0;
      ((float4*)x_ws)[(size_t)node * 32 + 16 + l16]   = x1;
    }
  }
}

// ---------------- per-edge 4-layer MLP via MFMA -> w (bf16, E x 160) -------
// layer-4 output stored PAIR-PACKED per edge row:
//   bf16 idx 2c+0 = w[p=0][c], 2c+1 = w[p=1][c]      (dword pair {w0,w1})
//   64 + 2c+0 = w[p=2][c], 64+2c+1 = w[p=3][c]       (dword pair {w2,w3})
//   128 + c   = w[p=4][c]
#define MLP_M 128
__global__ __launch_bounds__(256) void k_mlp(const float* __restrict__ ef,
                                             const unsigned short* __restrict__ frag,
                                             unsigned short* __restrict__ w_out,
                                             int E) {
  __shared__ __align__(16) unsigned short H[4][32][168];
  int tid = threadIdx.x;
  int wave = tid >> 6, lane = tid & 63;
  int quad = lane >> 4, l16 = lane & 15;
  int m0 = blockIdx.x * MLP_M + wave * 32;   // wave's first edge row
  unsigned short (*Hw)[168] = H[wave];

  // ---- layer 1: A = edge_feats rows (K=8 zero-padded to 32) ----
  bfrag a1[2];
#pragma unroll
  for (int mt = 0; mt < 2; ++mt) {
    float vals[8] = {0.f, 0.f, 0.f, 0.f, 0.f, 0.f, 0.f, 0.f};
    if (quad == 0) {
      int r = m0 + mt * 16 + l16;
      if (r > E - 1) r = E - 1;
      const float4* p = (const float4*)(ef + (size_t)r * 8);
      float4 u0 = p[0], u1 = p[1];
      vals[0] = u0.x; vals[1] = u0.y; vals[2] = u0.z; vals[3] = u0.w;
      vals[4] = u1.x; vals[5] = u1.y; vals[6] = u1.z; vals[7] = u1.w;
    }
    union { unsigned short s[8]; bfrag v; } pk;
#pragma unroll
    for (int j = 0; j < 8; ++j) pk.s[j] = f2bf(vals[j]);
    a1[mt] = pk.v;
  }
#pragma unroll
  for (int nt = 0; nt < 4; ++nt) {
    const bfrag* bp = (const bfrag*)(frag + ((size_t)(nt) * 64 + lane) * 8);
    bfrag b = *bp;
    ffrag acc0 = {0.f, 0.f, 0.f, 0.f}, acc1 = acc0;
    acc0 = __builtin_amdgcn_mfma_f32_16x16x32_bf16(a1[0], b, acc0, 0, 0, 0);
    acc1 = __builtin_amdgcn_mfma_f32_16x16x32_bf16(a1[1], b, acc1, 0, 0, 0);
#pragma unroll
    for (int r = 0; r < 4; ++r) {
      Hw[0 * 16 + quad * 4 + r][nt * 16 + l16] = f2bf(rsilu(acc0[r] * INV_SQRT8));
      Hw[1 * 16 + quad * 4 + r][nt * 16 + l16] = f2bf(rsilu(acc1[r] * INV_SQRT8));
    }
  }

  // ---- layers 2,3 (N=64) ----
  bfrag A[2][2];
#pragma unroll 1
  for (int L = 0; L < 2; ++L) {           // layers 2 and 3
    int fbase = 4 + L * 8;
#pragma unroll
    for (int mt = 0; mt < 2; ++mt)
#pragma unroll
      for (int ks = 0; ks < 2; ++ks)
        A[mt][ks] = *(const bfrag*)&Hw[mt * 16 + l16][ks * 32 + quad * 8];
#pragma unroll
    for (int nt = 0; nt < 4; ++nt) {
      ffrag acc0 = {0.f, 0.f, 0.f, 0.f}, acc1 = acc0;
#pragma unroll
      for (int ks = 0; ks < 2; ++ks) {
        bfrag b = *(const bfrag*)(frag + ((size_t)(fbase + nt * 2 + ks) * 64 + lane) * 8);
        acc0 = __builtin_amdgcn_mfma_f32_16x16x32_bf16(A[0][ks], b, acc0, 0, 0, 0);
        acc1 = __builtin_amdgcn_mfma_f32_16x16x32_bf16(A[1][ks], b, acc1, 0, 0, 0);
      }
#pragma unroll
      for (int r = 0; r < 4; ++r) {
        Hw[0 * 16 + quad * 4 + r][nt * 16 + l16] = f2bf(rsilu(acc0[r] * INV8));
        Hw[1 * 16 + quad * 4 + r][nt * 16 + l16] = f2bf(rsilu(acc1[r] * INV8));
      }
    }
  }

  // layer 4: w = h3 @ Wr3^T / 8, no activation; pair-packed column permutation
#pragma unroll
  for (int mt = 0; mt < 2; ++mt)
#pragma unroll
    for (int ks = 0; ks < 2; ++ks)
      A[mt][ks] = *(const bfrag*)&Hw[mt * 16 + l16][ks * 32 + quad * 8];
#pragma unroll 2
  for (int nt = 0; nt < 10; ++nt) {
    ffrag acc0 = {0.f, 0.f, 0.f, 0.f}, acc1 = acc0;
#pragma unroll
    for (int ks = 0; ks < 2; ++ks) {
      bfrag b = *(const bfrag*)(frag + ((size_t)(20 + nt * 2 + ks) * 64 + lane) * 8);
      acc0 = __builtin_amdgcn_mfma_f32_16x16x32_bf16(A[0][ks], b, acc0, 0, 0, 0);
      acc1 = __builtin_amdgcn_mfma_f32_16x16x32_bf16(A[1][ks], b, acc1, 0, 0, 0);
    }
    int col = nt * 16 + l16;
    int p = col >> 5, cc = col & 31;
    int ncol = (p < 4) ? ((p >> 1) * 64 + 2 * cc + (p & 1)) : (128 + cc);
#pragma unroll
    for (int r = 0; r < 4; ++r) {
      Hw[0 * 16 + quad * 4 + r][ncol] = f2bf(acc0[r] * INV8);
      Hw[1 * 16 + quad * 4 + r][ncol] = f2bf(acc1[r] * INV8);
    }
  }

  // flush: 32 rows x 160 bf16 -> global, 16 B chunks
#pragma unroll 2
  for (int it = 0; it < 10; ++it) {
    int c = it * 64 + lane;            // 0..639
    int row = c / 20, off = c % 20;
    int grow = m0 + row;
    uint4 v = *(const uint4*)&Hw[row][off * 8];
    if (grow < E)
      *(uint4*)(w_out + (size_t)grow * 160 + off * 8) = v;
  }
}

// ---------------- per-node message accumulation + W_second contraction ----------------
// v4 (= v3 minus the spill bug):
//  - 3 w loads/edge (pair-packed dwords), batch depth 4 (proven no-spill footprint),
//    NO forced min-occupancy bound.
//  - vectorized ds_read_b128 tail contraction.
__global__ __launch_bounds__(256) void k_msg(const unsigned short* __restrict__ w_ws,
                                             const float* __restrict__ x_ws,
                                             const float* __restrict__ ea,
                                             const int* __restrict__ idx_j,
                                             const int* __restrict__ row,
                                             const float* __restrict__ Ws0,
                                             const float* __restrict__ Ws1,
                                             float* __restrict__ out_msg) {
  __shared__ __align__(16) float msg[8][356];  // 352 comps, stride 356 (16B-aligned)
  __shared__ float W0T[64 * 33];    // [k*33+d]
  __shared__ float W1T[96 * 33];

  int tid = threadIdx.x;
  for (int t = tid; t < 2048; t += 256) {     // Ws0 (32x64) -> W0T[k][d]
    int d = t >> 6, k = t & 63;
    W0T[k * 33 + d] = Ws0[t];
  }
  for (int t = tid; t < 3072; t += 256) {     // Ws1 (32x96) -> W1T[k][d]
    int d = t / 96, k = t % 96;
    W1T[k * 33 + d] = Ws1[t];
  }

  int ln = tid >> 5, c = tid & 31;
  int n = blockIdx.x * 8 + ln;                // grid exactly N/8
  int e0 = row[n], e1 = row[n + 1];

  float m00 = 0.f, m01 = 0.f;
  float m10x = 0.f, m10y = 0.f, m10z = 0.f;
  float m11x = 0.f, m11y = 0.f, m11z = 0.f;
  float m12x = 0.f, m12y = 0.f, m12z = 0.f;

  for (int base = e0; base < e1; base += 32) {
    int rem = e1 - base;
    int cnt = rem < 32 ? rem : 32;
    // one coalesced load covers this chunk's indices (dup-clamped for c>=cnt)
    int jidx = base + (c < cnt ? c : cnt - 1);
    int j_c = __builtin_nontemporal_load(idx_j + jidx);

    for (int b = 0; b < cnt; b += 4) {
      int mvalid = cnt - b;                   // >= 1
      float4 xj[4], y4[4];
      unsigned d01[4], d23[4];
      unsigned short w4v[4];
#pragma unroll
      for (int t = 0; t < 4; ++t) {
        int tt = (t < mvalid) ? t : 0;        // clamp to a valid edge (loads safe)
        int e = base + b + tt;
        int j = __shfl(j_c, b + tt, 32);
        xj[t] = ((const float4*)x_ws)[(size_t)j * 32 + c];
        y4[t] = ((const float4*)ea)[e];
        const char* wb = (const char*)w_ws + (size_t)e * 320;
        d01[t] = *(const unsigned*)(wb + 4 * c);
        d23[t] = *(const unsigned*)(wb + 128 + 4 * c);
        w4v[t] = *(const unsigned short*)(wb + 256 + 2 * c);
      }
#pragma unroll
      for (int t = 0; t < 4; ++t) {
        if (t < mvalid) {
          float w0 = __uint_as_float(d01[t] << 16);
          float w1 = __uint_as_float(d01[t] & 0xffff0000u);
          float w2 = __uint_as_float(d23[t] << 16);
          float w3 = __uint_as_float(d23[t] & 0xffff0000u);
          float w4 = bf2f(w4v[t]);
          float4 x4 = xj[t], yy = y4[t];
          m00 += w0 * x4.x * yy.x;                                      // p0
          m01 += w3 * (x4.y * yy.y + x4.z * yy.z + x4.w * yy.w);        // p3
          m10x += w1 * x4.x * yy.y;
          m10y += w1 * x4.x * yy.z;
          m10z += w1 * x4.x * yy.w;                                     // p1
          m11x += w2 * x4.y * yy.x;
          m11y += w2 * x4.z * yy.x;
          m11z += w2 * x4.w * yy.x;                                     // p2
          float cx = x4.z * yy.w - x4.w * yy.z;
          float cy = x4.w * yy.y - x4.y * yy.w;
          float cz = x4.y * yy.z - x4.z * yy.y;
          m12x += w4 * cx;
          m12y += w4 * cy;
          m12z += w4 * cz;                                              // p4
        }
      }
    }
  }

  // msg row layout: [0..63] = {m00, m01}; [64 + m*96 + p'*32 + c], p' in {p1,p2,p4}
  msg[ln][c]      = m00;
  msg[ln][32 + c] = m01;
  msg[ln][64 + 0 * 96 +  0 + c] = m10x;
  msg[ln][64 + 0 * 96 + 32 + c] = m11x;
  msg[ln][64 + 0 * 96 + 64 + c] = m12x;
  msg[ln][64 + 1 * 96 +  0 + c] = m10y;
  msg[ln][64 + 1 * 96 + 32 + c] = m11y;
  msg[ln][64 + 1 * 96 + 64 + c] = m12y;
  msg[ln][64 + 2 * 96 +  0 + c] = m10z;
  msg[ln][64 + 2 * 96 + 32 + c] = m11z;
  msg[ln][64 + 2 * 96 + 64 + c] = m12z;
  __syncthreads();

  // out0[n][d=c] via float4 msg reads (broadcast b128)
  float o0 = 0.f;
#pragma unroll 4
  for (int k4 = 0; k4 < 16; ++k4) {
    float4 mk = *(const float4*)&msg[ln][4 * k4];
    o0 += mk.x * W0T[(4 * k4 + 0) * 33 + c];
    o0 += mk.y * W0T[(4 * k4 + 1) * 33 + c];
    o0 += mk.z * W0T[(4 * k4 + 2) * 33 + c];
    o0 += mk.w * W0T[(4 * k4 + 3) * 33 + c];
  }
  // out1[n][d=c][m]
  float o1x = 0.f, o1y = 0.f, o1z = 0.f;
#pragma unroll 4
  for (int k4 = 0; k4 < 24; ++k4) {
    float4 ax = *(const float4*)&msg[ln][64 + 0 * 96 + 4 * k4];
    float4 ay = *(const float4*)&msg[ln][64 + 1 * 96 + 4 * k4];
    float4 az = *(const float4*)&msg[ln][64 + 2 * 96 + 4 * k4];
#pragma unroll
    for (int i = 0; i < 4; ++i) {
      float wv = W1T[(4 * k4 + i) * 33 + c];
      float mx = (i == 0) ? ax.x : (i == 1) ? ax.y : (i == 2) ? ax.z : ax.w;
      float my = (i == 0) ? ay.x : (i == 1) ? ay.y : (i == 2) ? ay.z : ay.w;
      float mz = (i == 0) ? az.x : (i == 1) ? az.y : (i == 2) ? az.z : az.w;
      o1x += mx * wv;
      o1y += my * wv;
      o1z += mz * wv;
    }
  }
  float4 res = {o0 * INV8 * INV_AVG, o1x * INV_SQRT96 * INV_AVG,
                o1y * INV_SQRT96 * INV_AVG, o1z * INV_SQRT96 * INV_AVG};
  ((float4*)out_msg)[(size_t)n * 32 + c] = res;
}

extern "C" void kernel_launch(void* const* d_in, const int* in_sizes, int n_in,
                              void* d_out, int out_size, void* d_ws, size_t ws_size,
                              hipStream_t stream) {
  const float* node_attrs = (const float*)d_in[0];
  const float* node_feats = (const float*)d_in[1];
  const float* edge_attrs = (const float*)d_in[2];
  const float* edge_feats = (const float*)d_in[3];
  const float* W_first    = (const float*)d_in[4];
  const float* Wr0        = (const float*)d_in[5];
  const float* Wr1        = (const float*)d_in[6];
  const float* Wr2        = (const float*)d_in[7];
  const float* Wr3        = (const float*)d_in[8];
  const float* Ws0        = (const float*)d_in[9];
  const float* Ws1        = (const float*)d_in[10];
  const float* Wsk        = (const float*)d_in[11];
  const int*   idx_i      = (const int*)d_in[12];
  const int*   idx_j      = (const int*)d_in[13];
  float* out = (float*)d_out;

  char* ws = (char*)d_ws;
  float*          x_ws   = (float*)(ws + OFF_X);
  int*            rowp   = (int*)(ws + OFF_ROW);
  unsigned short* fragp  = (unsigned short*)(ws + OFF_FRAG);
  unsigned short* frag2p = (unsigned short*)(ws + OFF_FRAG2);
  unsigned short* w_ws   = (unsigned short*)(ws + OFF_W);

  k_rowstart<<<(N_EDGES + 255) / 256, 256, 0, stream>>>(idx_i, rowp, N_EDGES, N_NODES);
  k_prep<<<80, 256, 0, stream>>>(Wr0, Wr1, Wr2, Wr3, fragp);
  k_prep2<<<176, 256, 0, stream>>>(Wsk, W_first, frag2p);
  k_node_mfma<<<(N_NODES + 31) / 32, 256, 0, stream>>>(node_attrs, node_feats,
                                                       frag2p, out + 6400000, x_ws);
  k_mlp<<<(N_EDGES + MLP_M - 1) / MLP_M, 256, 0, stream>>>(edge_feats, fragp,
                                                           w_ws, N_EDGES);
  k_msg<<<N_NODES / 8, 256, 0, stream>>>(w_ws, x_ws, edge_attrs, idx_j, rowp,
                                         Ws0, Ws1, out);
}

// Round 4
// 345.149 us; speedup vs baseline: 1.1884x; 1.0729x over previous
//
#include <hip/hip_runtime.h>
#include <math.h>

#define N_NODES 50000
#define N_EDGES 600000

constexpr float RS          = 1.6765324703310907f;
constexpr float INV_SQRT8   = 0.35355339059327373f;
constexpr float INV8        = 0.125f;
constexpr float INV_SQRT320 = 0.05590169943749474f;
constexpr float INV_SQRT32  = 0.17677669529663687f;
constexpr float INV_SQRT96  = 0.10206207261596575f;
constexpr float INV_AVG     = 1.0f / 12.0f;

// ws layout (bytes)
constexpr size_t OFF_X     = 0;           // N*32 float4 = 25,600,000
constexpr size_t OFF_ROW   = 25600000;    // (N+1) int   =    200,004
constexpr size_t OFF_FRAG  = 25800064;    // 40 frag-sets * 512 bf16 = 40,960
constexpr size_t OFF_FRAG2 = 25841024;    // 88 frag-sets * 512 bf16 = 90,112
constexpr size_t OFF_W     = 25931136;    // E*160 bf16  = 192,000,000

typedef __attribute__((ext_vector_type(8))) short bfrag;   // 8 bf16 (4 VGPRs)
typedef __attribute__((ext_vector_type(4))) float ffrag;   // 4 fp32 acc

// fast rescaled-SiLU: RS*z/(1+exp(-z)) with v_exp2 + v_rcp (1-ulp approx,
// >> bf16 output precision). Saves the ~9-inst IEEE divide sequence.
__device__ __forceinline__ float rsilu(float z) {
  float t = __builtin_amdgcn_exp2f(z * -1.44269504088896341f);
  return (RS * z) * __builtin_amdgcn_rcpf(1.0f + t);
}
__device__ __forceinline__ unsigned short f2bf(float x) {
  unsigned u = __float_as_uint(x);
  u += 0x7FFFu + ((u >> 16) & 1u);
  return (unsigned short)(u >> 16);
}
__device__ __forceinline__ float bf2f(unsigned short u) {
  return __uint_as_float(((unsigned)u) << 16);
}

// ---------------- CSR row offsets from sorted idx_i ----------------
__global__ __launch_bounds__(256) void k_rowstart(const int* __restrict__ idx_i,
                                                  int* __restrict__ row,
                                                  int E, int N) {
  int e = blockIdx.x * 256 + threadIdx.x;
  if (e >= E) return;
  int cur  = idx_i[e];
  int prev = (e == 0) ? -1 : idx_i[e - 1];
  for (int n = prev + 1; n <= cur; ++n) row[n] = e;
  if (e == E - 1) {
    for (int n = cur + 1; n <= N; ++n) row[n] = E;
  }
}

// ---------------- pre-pack MLP weights into MFMA B-fragment order ----------
// v5: layer scale constants folded into the weights (layer1 *INV_SQRT8,
// layers 2-4 *INV8) so k_mlp skips the per-activation scale mul.
__global__ __launch_bounds__(256) void k_prep(const float* __restrict__ Wr0,
                                              const float* __restrict__ Wr1,
                                              const float* __restrict__ Wr2,
                                              const float* __restrict__ Wr3,
                                              unsigned short* __restrict__ frag) {
  int t = blockIdx.x * 256 + threadIdx.x;   // exactly 40*512 = 20480 threads
  int f    = t >> 9;
  int lane = (t >> 3) & 63;
  int j    = t & 7;
  int n16  = lane & 15, quad = lane >> 4;
  float v;
  if (f < 4) {
    int d = f * 16 + n16, k = quad * 8 + j;
    v = (k < 8) ? Wr0[d * 8 + k] * INV_SQRT8 : 0.f;
  } else if (f < 12) {
    int ff = f - 4, ntile = ff >> 1, ks = ff & 1;
    int d = ntile * 16 + n16, k = ks * 32 + quad * 8 + j;
    v = Wr1[d * 64 + k] * INV8;
  } else if (f < 20) {
    int ff = f - 12, ntile = ff >> 1, ks = ff & 1;
    int d = ntile * 16 + n16, k = ks * 32 + quad * 8 + j;
    v = Wr2[d * 64 + k] * INV8;
  } else {
    int ff = f - 20, ntile = ff >> 1, ks = ff & 1;
    int d = ntile * 16 + n16, k = ks * 32 + quad * 8 + j;
    v = Wr3[d * 64 + k] * INV8;
  }
  frag[t] = f2bf(v);
}

// ---------------- pre-pack node weights: B2 [K=352][128 cols], frag order ---
__global__ __launch_bounds__(256) void k_prep2(const float* __restrict__ Wsk,
                                               const float* __restrict__ Wf,
                                               unsigned short* __restrict__ frag2) {
  int t = blockIdx.x * 256 + threadIdx.x;   // exactly 88*512 = 45056 threads
  int f    = t >> 9;
  int lane = (t >> 3) & 63;
  int j    = t & 7;
  int n16  = lane & 15, quad = lane >> 4;
  int ks = f >> 3, nt = f & 7;
  int k   = ks * 32 + quad * 8 + j;
  int col = nt * 16 + n16;
  float v = 0.f;
  if (k < 320) {
    int vv = k >> 5, c = k & 31;
    if (col < 32)       v = Wsk[(c * 10 + vv) * 32 + col] * INV_SQRT320;
    else if (col < 64)  v = Wsk[((32 + c) * 10 + vv) * 32 + (col - 32)] * INV_SQRT320;
  } else {
    int c = k - 320;
    if (col >= 96)      v = Wf[1024 + (col - 96) * 32 + c] * INV_SQRT32;
    else if (col >= 64) v = Wf[(col - 64) * 32 + c] * INV_SQRT32;
  }
  frag2[t] = f2bf(v);
}

// ---------------- per-node sc + x via MFMA ----------------
__global__ __launch_bounds__(256) void k_node_mfma(const float* __restrict__ attrs,
                                                   const float* __restrict__ feats,
                                                   const unsigned short* __restrict__ frag2,
                                                   float* __restrict__ out_sc,
                                                   float* __restrict__ x_ws) {
  int tid = threadIdx.x;
  int wave = tid >> 6, lane = tid & 63;
  int quad = lane >> 4, l16 = lane & 15;
  int nb = blockIdx.x * 32 + wave * 8;

  float featsF[2][8];
  float a[2][10];
#pragma unroll
  for (int mt = 0; mt < 2; ++mt) {
    int nodeA = nb + mt * 4 + (l16 >> 2);
    if (nodeA > N_NODES - 1) nodeA = N_NODES - 1;
    int m = l16 & 3;
#pragma unroll
    for (int j = 0; j < 8; ++j)
      featsF[mt][j] = feats[(size_t)nodeA * 128 + (quad * 8 + j) * 4 + m];
#pragma unroll
    for (int v = 0; v < 10; ++v) a[mt][v] = attrs[nodeA * 10 + v];
  }

  ffrag acc[2][8];
#pragma unroll
  for (int mt = 0; mt < 2; ++mt)
#pragma unroll
    for (int nt = 0; nt < 8; ++nt) acc[mt][nt] = (ffrag){0.f, 0.f, 0.f, 0.f};

#pragma unroll
  for (int ks = 0; ks < 11; ++ks) {
    bfrag Ab[2];
#pragma unroll
    for (int mt = 0; mt < 2; ++mt) {
      union { unsigned short s8[8]; bfrag v; } pk;
#pragma unroll
      for (int j = 0; j < 8; ++j) {
        float val = (ks < 10) ? a[mt][ks] * featsF[mt][j] : featsF[mt][j];
        pk.s8[j] = f2bf(val);
      }
      Ab[mt] = pk.v;
    }
#pragma unroll
    for (int nt = 0; nt < 8; ++nt) {
      bfrag B = *(const bfrag*)(frag2 + ((size_t)(ks * 8 + nt) * 64 + lane) * 8);
      acc[0][nt] = __builtin_amdgcn_mfma_f32_16x16x32_bf16(Ab[0], B, acc[0][nt], 0, 0, 0);
      acc[1][nt] = __builtin_amdgcn_mfma_f32_16x16x32_bf16(Ab[1], B, acc[1][nt], 0, 0, 0);
    }
  }

#pragma unroll
  for (int mt = 0; mt < 2; ++mt) {
    int node = nb + mt * 4 + quad;
    if (node < N_NODES) {
      float4 sc0 = {acc[mt][0][0], acc[mt][2][1], acc[mt][2][2], acc[mt][2][3]};
      float4 sc1 = {acc[mt][1][0], acc[mt][3][1], acc[mt][3][2], acc[mt][3][3]};
      float4 x0  = {acc[mt][4][0], acc[mt][6][1], acc[mt][6][2], acc[mt][6][3]};
      float4 x1  = {acc[mt][5][0], acc[mt][7][1], acc[mt][7][2], acc[mt][7][3]};
      ((float4*)out_sc)[(size_t)node * 32 + l16]      = sc0;
      ((float4*)out_sc)[(size_t)node * 32 + 16 + l16] = sc1;
      ((float4*)x_ws)[(size_t)node * 32 + l16]        = x0;
      ((float4*)x_ws)[(size_t)node * 32 + 16 + l16]   = x1;
    }
  }
}

// ---------------- per-edge 4-layer MLP via MFMA -> w (bf16, E x 160) -------
// layer-4 output stored PAIR-PACKED per edge row:
//   bf16 idx 2c+0 = w[p=0][c], 2c+1 = w[p=1][c]      (dword pair {w0,w1})
//   64 + 2c+0 = w[p=2][c], 64+2c+1 = w[p=3][c]       (dword pair {w2,w3})
//   128 + c   = w[p=4][c]
// v5: scale constants pre-folded into frags; fast rsilu; incremental flush idx.
#define MLP_M 128
__global__ __launch_bounds__(256) void k_mlp(const float* __restrict__ ef,
                                             const unsigned short* __restrict__ frag,
                                             unsigned short* __restrict__ w_out,
                                             int E) {
  __shared__ __align__(16) unsigned short H[4][32][168];
  int tid = threadIdx.x;
  int wave = tid >> 6, lane = tid & 63;
  int quad = lane >> 4, l16 = lane & 15;
  int m0 = blockIdx.x * MLP_M + wave * 32;   // wave's first edge row
  unsigned short (*Hw)[168] = H[wave];

  // ---- layer 1: A = edge_feats rows (K=8 zero-padded to 32) ----
  bfrag a1[2];
#pragma unroll
  for (int mt = 0; mt < 2; ++mt) {
    float vals[8] = {0.f, 0.f, 0.f, 0.f, 0.f, 0.f, 0.f, 0.f};
    if (quad == 0) {
      int r = m0 + mt * 16 + l16;
      if (r > E - 1) r = E - 1;
      const float4* p = (const float4*)(ef + (size_t)r * 8);
      float4 u0 = p[0], u1 = p[1];
      vals[0] = u0.x; vals[1] = u0.y; vals[2] = u0.z; vals[3] = u0.w;
      vals[4] = u1.x; vals[5] = u1.y; vals[6] = u1.z; vals[7] = u1.w;
    }
    union { unsigned short s[8]; bfrag v; } pk;
#pragma unroll
    for (int j = 0; j < 8; ++j) pk.s[j] = f2bf(vals[j]);
    a1[mt] = pk.v;
  }
#pragma unroll
  for (int nt = 0; nt < 4; ++nt) {
    const bfrag* bp = (const bfrag*)(frag + ((size_t)(nt) * 64 + lane) * 8);
    bfrag b = *bp;
    ffrag acc0 = {0.f, 0.f, 0.f, 0.f}, acc1 = acc0;
    acc0 = __builtin_amdgcn_mfma_f32_16x16x32_bf16(a1[0], b, acc0, 0, 0, 0);
    acc1 = __builtin_amdgcn_mfma_f32_16x16x32_bf16(a1[1], b, acc1, 0, 0, 0);
#pragma unroll
    for (int r = 0; r < 4; ++r) {
      Hw[0 * 16 + quad * 4 + r][nt * 16 + l16] = f2bf(rsilu(acc0[r]));
      Hw[1 * 16 + quad * 4 + r][nt * 16 + l16] = f2bf(rsilu(acc1[r]));
    }
  }

  // ---- layers 2,3 (N=64) ----
  bfrag A[2][2];
#pragma unroll 1
  for (int L = 0; L < 2; ++L) {           // layers 2 and 3
    int fbase = 4 + L * 8;
#pragma unroll
    for (int mt = 0; mt < 2; ++mt)
#pragma unroll
      for (int ks = 0; ks < 2; ++ks)
        A[mt][ks] = *(const bfrag*)&Hw[mt * 16 + l16][ks * 32 + quad * 8];
#pragma unroll
    for (int nt = 0; nt < 4; ++nt) {
      ffrag acc0 = {0.f, 0.f, 0.f, 0.f}, acc1 = acc0;
#pragma unroll
      for (int ks = 0; ks < 2; ++ks) {
        bfrag b = *(const bfrag*)(frag + ((size_t)(fbase + nt * 2 + ks) * 64 + lane) * 8);
        acc0 = __builtin_amdgcn_mfma_f32_16x16x32_bf16(A[0][ks], b, acc0, 0, 0, 0);
        acc1 = __builtin_amdgcn_mfma_f32_16x16x32_bf16(A[1][ks], b, acc1, 0, 0, 0);
      }
#pragma unroll
      for (int r = 0; r < 4; ++r) {
        Hw[0 * 16 + quad * 4 + r][nt * 16 + l16] = f2bf(rsilu(acc0[r]));
        Hw[1 * 16 + quad * 4 + r][nt * 16 + l16] = f2bf(rsilu(acc1[r]));
      }
    }
  }

  // layer 4: w = h3 @ Wr3^T / 8 (scale pre-folded), no activation;
  // pair-packed column permutation
#pragma unroll
  for (int mt = 0; mt < 2; ++mt)
#pragma unroll
    for (int ks = 0; ks < 2; ++ks)
      A[mt][ks] = *(const bfrag*)&Hw[mt * 16 + l16][ks * 32 + quad * 8];
#pragma unroll 2
  for (int nt = 0; nt < 10; ++nt) {
    ffrag acc0 = {0.f, 0.f, 0.f, 0.f}, acc1 = acc0;
#pragma unroll
    for (int ks = 0; ks < 2; ++ks) {
      bfrag b = *(const bfrag*)(frag + ((size_t)(20 + nt * 2 + ks) * 64 + lane) * 8);
      acc0 = __builtin_amdgcn_mfma_f32_16x16x32_bf16(A[0][ks], b, acc0, 0, 0, 0);
      acc1 = __builtin_amdgcn_mfma_f32_16x16x32_bf16(A[1][ks], b, acc1, 0, 0, 0);
    }
    int col = nt * 16 + l16;
    int p = col >> 5, cc = col & 31;
    int ncol = (p < 4) ? ((p >> 1) * 64 + 2 * cc + (p & 1)) : (128 + cc);
#pragma unroll
    for (int r = 0; r < 4; ++r) {
      Hw[0 * 16 + quad * 4 + r][ncol] = f2bf(acc0[r]);
      Hw[1 * 16 + quad * 4 + r][ncol] = f2bf(acc1[r]);
    }
  }

  // flush: 32 rows x 160 bf16 -> global, 16 B chunks; incremental row/off
  // (c = it*64+lane; 64 = 3*20 + 4)
  {
    int row = lane / 20, off = lane - row * 20;
    int grow_base = m0;
#pragma unroll 2
    for (int it = 0; it < 10; ++it) {
      int grow = grow_base + row;
      uint4 v = *(const uint4*)&Hw[row][off * 8];
      if (grow < E)
        *(uint4*)(w_out + (size_t)grow * 160 + off * 8) = v;
      off += 4;
      row += 3;
      if (off >= 20) { off -= 20; row += 1; }
    }
  }
}

// ---------------- per-node message accumulation + W_second contraction ----------------
//  - 3 w loads/edge (pair-packed dwords), batch depth 4 (proven no-spill),
//    no forced min-occupancy bound.
//  - vectorized ds_read_b128 tail contraction.
__global__ __launch_bounds__(256) void k_msg(const unsigned short* __restrict__ w_ws,
                                             const float* __restrict__ x_ws,
                                             const float* __restrict__ ea,
                                             const int* __restrict__ idx_j,
                                             const int* __restrict__ row,
                                             const float* __restrict__ Ws0,
                                             const float* __restrict__ Ws1,
                                             float* __restrict__ out_msg) {
  __shared__ __align__(16) float msg[8][356];  // 352 comps, stride 356 (16B-aligned)
  __shared__ float W0T[64 * 33];    // [k*33+d]
  __shared__ float W1T[96 * 33];

  int tid = threadIdx.x;
  for (int t = tid; t < 2048; t += 256) {     // Ws0 (32x64) -> W0T[k][d]
    int d = t >> 6, k = t & 63;
    W0T[k * 33 + d] = Ws0[t];
  }
  for (int t = tid; t < 3072; t += 256) {     // Ws1 (32x96) -> W1T[k][d]
    int d = t / 96, k = t % 96;
    W1T[k * 33 + d] = Ws1[t];
  }

  int ln = tid >> 5, c = tid & 31;
  int n = blockIdx.x * 8 + ln;                // grid exactly N/8
  int e0 = row[n], e1 = row[n + 1];

  float m00 = 0.f, m01 = 0.f;
  float m10x = 0.f, m10y = 0.f, m10z = 0.f;
  float m11x = 0.f, m11y = 0.f, m11z = 0.f;
  float m12x = 0.f, m12y = 0.f, m12z = 0.f;

  for (int base = e0; base < e1; base += 32) {
    int rem = e1 - base;
    int cnt = rem < 32 ? rem : 32;
    // one coalesced load covers this chunk's indices (dup-clamped for c>=cnt)
    int jidx = base + (c < cnt ? c : cnt - 1);
    int j_c = __builtin_nontemporal_load(idx_j + jidx);

    for (int b = 0; b < cnt; b += 4) {
      int mvalid = cnt - b;                   // >= 1
      float4 xj[4], y4[4];
      unsigned d01[4], d23[4];
      unsigned short w4v[4];
#pragma unroll
      for (int t = 0; t < 4; ++t) {
        int tt = (t < mvalid) ? t : 0;        // clamp to a valid edge (loads safe)
        int e = base + b + tt;
        int j = __shfl(j_c, b + tt, 32);
        xj[t] = ((const float4*)x_ws)[(size_t)j * 32 + c];
        y4[t] = ((const float4*)ea)[e];
        const char* wb = (const char*)w_ws + (size_t)e * 320;
        d01[t] = *(const unsigned*)(wb + 4 * c);
        d23[t] = *(const unsigned*)(wb + 128 + 4 * c);
        w4v[t] = *(const unsigned short*)(wb + 256 + 2 * c);
      }
#pragma unroll
      for (int t = 0; t < 4; ++t) {
        if (t < mvalid) {
          float w0 = __uint_as_float(d01[t] << 16);
          float w1 = __uint_as_float(d01[t] & 0xffff0000u);
          float w2 = __uint_as_float(d23[t] << 16);
          float w3 = __uint_as_float(d23[t] & 0xffff0000u);
          float w4 = bf2f(w4v[t]);
          float4 x4 = xj[t], yy = y4[t];
          m00 += w0 * x4.x * yy.x;                                      // p0
          m01 += w3 * (x4.y * yy.y + x4.z * yy.z + x4.w * yy.w);        // p3
          m10x += w1 * x4.x * yy.y;
          m10y += w1 * x4.x * yy.z;
          m10z += w1 * x4.x * yy.w;                                     // p1
          m11x += w2 * x4.y * yy.x;
          m11y += w2 * x4.z * yy.x;
          m11z += w2 * x4.w * yy.x;                                     // p2
          float cx = x4.z * yy.w - x4.w * yy.z;
          float cy = x4.w * yy.y - x4.y * yy.w;
          float cz = x4.y * yy.z - x4.z * yy.y;
          m12x += w4 * cx;
          m12y += w4 * cy;
          m12z += w4 * cz;                                              // p4
        }
      }
    }
  }

  // msg row layout: [0..63] = {m00, m01}; [64 + m*96 + p'*32 + c], p' in {p1,p2,p4}
  msg[ln][c]      = m00;
  msg[ln][32 + c] = m01;
  msg[ln][64 + 0 * 96 +  0 + c] = m10x;
  msg[ln][64 + 0 * 96 + 32 + c] = m11x;
  msg[ln][64 + 0 * 96 + 64 + c] = m12x;
  msg[ln][64 + 1 * 96 +  0 + c] = m10y;
  msg[ln][64 + 1 * 96 + 32 + c] = m11y;
  msg[ln][64 + 1 * 96 + 64 + c] = m12y;
  msg[ln][64 + 2 * 96 +  0 + c] = m10z;
  msg[ln][64 + 2 * 96 + 32 + c] = m11z;
  msg[ln][64 + 2 * 96 + 64 + c] = m12z;
  __syncthreads();

  // out0[n][d=c] via float4 msg reads (broadcast b128)
  float o0 = 0.f;
#pragma unroll 4
  for (int k4 = 0; k4 < 16; ++k4) {
    float4 mk = *(const float4*)&msg[ln][4 * k4];
    o0 += mk.x * W0T[(4 * k4 + 0) * 33 + c];
    o0 += mk.y * W0T[(4 * k4 + 1) * 33 + c];
    o0 += mk.z * W0T[(4 * k4 + 2) * 33 + c];
    o0 += mk.w * W0T[(4 * k4 + 3) * 33 + c];
  }
  // out1[n][d=c][m]
  float o1x = 0.f, o1y = 0.f, o1z = 0.f;
#pragma unroll 4
  for (int k4 = 0; k4 < 24; ++k4) {
    float4 ax = *(const float4*)&msg[ln][64 + 0 * 96 + 4 * k4];
    float4 ay = *(const float4*)&msg[ln][64 + 1 * 96 + 4 * k4];
    float4 az = *(const float4*)&msg[ln][64 + 2 * 96 + 4 * k4];
#pragma unroll
    for (int i = 0; i < 4; ++i) {
      float wv = W1T[(4 * k4 + i) * 33 + c];
      float mx = (i == 0) ? ax.x : (i == 1) ? ax.y : (i == 2) ? ax.z : ax.w;
      float my = (i == 0) ? ay.x : (i == 1) ? ay.y : (i == 2) ? ay.z : ay.w;
      float mz = (i == 0) ? az.x : (i == 1) ? az.y : (i == 2) ? az.z : az.w;
      o1x += mx * wv;
      o1y += my * wv;
      o1z += mz * wv;
    }
  }
  float4 res = {o0 * INV8 * INV_AVG, o1x * INV_SQRT96 * INV_AVG,
                o1y * INV_SQRT96 * INV_AVG, o1z * INV_SQRT96 * INV_AVG};
  ((float4*)out_msg)[(size_t)n * 32 + c] = res;
}

extern "C" void kernel_launch(void* const* d_in, const int* in_sizes, int n_in,
                              void* d_out, int out_size, void* d_ws, size_t ws_size,
                              hipStream_t stream) {
  const float* node_attrs = (const float*)d_in[0];
  const float* node_feats = (const float*)d_in[1];
  const float* edge_attrs = (const float*)d_in[2];
  const float* edge_feats = (const float*)d_in[3];
  const float* W_first    = (const float*)d_in[4];
  const float* Wr0        = (const float*)d_in[5];
  const float* Wr1        = (const float*)d_in[6];
  const float* Wr2        = (const float*)d_in[7];
  const float* Wr3        = (const float*)d_in[8];
  const float* Ws0        = (const float*)d_in[9];
  const float* Ws1        = (const float*)d_in[10];
  const float* Wsk        = (const float*)d_in[11];
  const int*   idx_i      = (const int*)d_in[12];
  const int*   idx_j      = (const int*)d_in[13];
  float* out = (float*)d_out;

  char* ws = (char*)d_ws;
  float*          x_ws   = (float*)(ws + OFF_X);
  int*            rowp   = (int*)(ws + OFF_ROW);
  unsigned short* fragp  = (unsigned short*)(ws + OFF_FRAG);
  unsigned short* frag2p = (unsigned short*)(ws + OFF_FRAG2);
  unsigned short* w_ws   = (unsigned short*)(ws + OFF_W);

  k_rowstart<<<(N_EDGES + 255) / 256, 256, 0, stream>>>(idx_i, rowp, N_EDGES, N_NODES);
  k_prep<<<80, 256, 0, stream>>>(Wr0, Wr1, Wr2, Wr3, fragp);
  k_prep2<<<176, 256, 0, stream>>>(Wsk, W_first, frag2p);
  k_node_mfma<<<(N_NODES + 31) / 32, 256, 0, stream>>>(node_attrs, node_feats,
                                                       frag2p, out + 6400000, x_ws);
  k_mlp<<<(N_EDGES + MLP_M - 1) / MLP_M, 256, 0, stream>>>(edge_feats, fragp,
                                                           w_ws, N_EDGES);
  k_msg<<<N_NODES / 8, 256, 0, stream>>>(w_ws, x_ws, edge_attrs, idx_j, rowp,
                                         Ws0, Ws1, out);
}

// Round 5
// 333.744 us; speedup vs baseline: 1.2290x; 1.0342x over previous
//
#include <hip/hip_runtime.h>
#include <math.h>

#define N_NODES 50000
#define N_EDGES 600000

constexpr float RS          = 1.6765324703310907f;
constexpr float INV_SQRT8   = 0.35355339059327373f;
constexpr float INV8        = 0.125f;
constexpr float INV_SQRT320 = 0.05590169943749474f;
constexpr float INV_SQRT32  = 0.17677669529663687f;
constexpr float INV_SQRT96  = 0.10206207261596575f;
constexpr float INV_AVG     = 1.0f / 12.0f;

// ws layout (bytes)
constexpr size_t OFF_X     = 0;           // N*32 float4 = 25,600,000
constexpr size_t OFF_ROW   = 25600000;    // (N+1) int   =    200,004
constexpr size_t OFF_FRAG  = 25800064;    // 40 frag-sets * 512 bf16 = 40,960
constexpr size_t OFF_FRAG2 = 25841024;    // 88 frag-sets * 512 bf16 = 90,112
constexpr size_t OFF_W     = 25931136;    // E*160 bf16  = 192,000,000

typedef __attribute__((ext_vector_type(8))) short bfrag;   // 8 bf16 (4 VGPRs)
typedef __attribute__((ext_vector_type(4))) float ffrag;   // 4 fp32 acc

// fast rescaled-SiLU: RS*z/(1+exp(-z)) with v_exp2 + v_rcp (1-ulp approx,
// >> bf16 output precision). Saves the ~9-inst IEEE divide sequence.
__device__ __forceinline__ float rsilu(float z) {
  float t = __builtin_amdgcn_exp2f(z * -1.44269504088896341f);
  return (RS * z) * __builtin_amdgcn_rcpf(1.0f + t);
}
__device__ __forceinline__ unsigned short f2bf(float x) {
  unsigned u = __float_as_uint(x);
  u += 0x7FFFu + ((u >> 16) & 1u);
  return (unsigned short)(u >> 16);
}
__device__ __forceinline__ float bf2f(unsigned short u) {
  return __uint_as_float(((unsigned)u) << 16);
}

// ---------------- CSR row offsets from sorted idx_i ----------------
__global__ __launch_bounds__(256) void k_rowstart(const int* __restrict__ idx_i,
                                                  int* __restrict__ row,
                                                  int E, int N) {
  int e = blockIdx.x * 256 + threadIdx.x;
  if (e >= E) return;
  int cur  = idx_i[e];
  int prev = (e == 0) ? -1 : idx_i[e - 1];
  for (int n = prev + 1; n <= cur; ++n) row[n] = e;
  if (e == E - 1) {
    for (int n = cur + 1; n <= N; ++n) row[n] = E;
  }
}

// ---------------- pre-pack MLP weights into MFMA B-fragment order ----------
// layer scale constants folded into the weights (layer1 *INV_SQRT8,
// layers 2-4 *INV8) so k_mlp skips the per-activation scale mul.
__global__ __launch_bounds__(256) void k_prep(const float* __restrict__ Wr0,
                                              const float* __restrict__ Wr1,
                                              const float* __restrict__ Wr2,
                                              const float* __restrict__ Wr3,
                                              unsigned short* __restrict__ frag) {
  int t = blockIdx.x * 256 + threadIdx.x;   // exactly 40*512 = 20480 threads
  int f    = t >> 9;
  int lane = (t >> 3) & 63;
  int j    = t & 7;
  int n16  = lane & 15, quad = lane >> 4;
  float v;
  if (f < 4) {
    int d = f * 16 + n16, k = quad * 8 + j;
    v = (k < 8) ? Wr0[d * 8 + k] * INV_SQRT8 : 0.f;
  } else if (f < 12) {
    int ff = f - 4, ntile = ff >> 1, ks = ff & 1;
    int d = ntile * 16 + n16, k = ks * 32 + quad * 8 + j;
    v = Wr1[d * 64 + k] * INV8;
  } else if (f < 20) {
    int ff = f - 12, ntile = ff >> 1, ks = ff & 1;
    int d = ntile * 16 + n16, k = ks * 32 + quad * 8 + j;
    v = Wr2[d * 64 + k] * INV8;
  } else {
    int ff = f - 20, ntile = ff >> 1, ks = ff & 1;
    int d = ntile * 16 + n16, k = ks * 32 + quad * 8 + j;
    v = Wr3[d * 64 + k] * INV8;
  }
  frag[t] = f2bf(v);
}

// ---------------- pre-pack node weights: B2 [K=352][128 cols], frag order ---
__global__ __launch_bounds__(256) void k_prep2(const float* __restrict__ Wsk,
                                               const float* __restrict__ Wf,
                                               unsigned short* __restrict__ frag2) {
  int t = blockIdx.x * 256 + threadIdx.x;   // exactly 88*512 = 45056 threads
  int f    = t >> 9;
  int lane = (t >> 3) & 63;
  int j    = t & 7;
  int n16  = lane & 15, quad = lane >> 4;
  int ks = f >> 3, nt = f & 7;
  int k   = ks * 32 + quad * 8 + j;
  int col = nt * 16 + n16;
  float v = 0.f;
  if (k < 320) {
    int vv = k >> 5, c = k & 31;
    if (col < 32)       v = Wsk[(c * 10 + vv) * 32 + col] * INV_SQRT320;
    else if (col < 64)  v = Wsk[((32 + c) * 10 + vv) * 32 + (col - 32)] * INV_SQRT320;
  } else {
    int c = k - 320;
    if (col >= 96)      v = Wf[1024 + (col - 96) * 32 + c] * INV_SQRT32;
    else if (col >= 64) v = Wf[(col - 64) * 32 + c] * INV_SQRT32;
  }
  frag2[t] = f2bf(v);
}

// ---------------- per-node sc + x via MFMA ----------------
__global__ __launch_bounds__(256) void k_node_mfma(const float* __restrict__ attrs,
                                                   const float* __restrict__ feats,
                                                   const unsigned short* __restrict__ frag2,
                                                   float* __restrict__ out_sc,
                                                   float* __restrict__ x_ws) {
  int tid = threadIdx.x;
  int wave = tid >> 6, lane = tid & 63;
  int quad = lane >> 4, l16 = lane & 15;
  int nb = blockIdx.x * 32 + wave * 8;

  float featsF[2][8];
  float a[2][10];
#pragma unroll
  for (int mt = 0; mt < 2; ++mt) {
    int nodeA = nb + mt * 4 + (l16 >> 2);
    if (nodeA > N_NODES - 1) nodeA = N_NODES - 1;
    int m = l16 & 3;
#pragma unroll
    for (int j = 0; j < 8; ++j)
      featsF[mt][j] = feats[(size_t)nodeA * 128 + (quad * 8 + j) * 4 + m];
#pragma unroll
    for (int v = 0; v < 10; ++v) a[mt][v] = attrs[nodeA * 10 + v];
  }

  ffrag acc[2][8];
#pragma unroll
  for (int mt = 0; mt < 2; ++mt)
#pragma unroll
    for (int nt = 0; nt < 8; ++nt) acc[mt][nt] = (ffrag){0.f, 0.f, 0.f, 0.f};

#pragma unroll
  for (int ks = 0; ks < 11; ++ks) {
    bfrag Ab[2];
#pragma unroll
    for (int mt = 0; mt < 2; ++mt) {
      union { unsigned short s8[8]; bfrag v; } pk;
#pragma unroll
      for (int j = 0; j < 8; ++j) {
        float val = (ks < 10) ? a[mt][ks] * featsF[mt][j] : featsF[mt][j];
        pk.s8[j] = f2bf(val);
      }
      Ab[mt] = pk.v;
    }
#pragma unroll
    for (int nt = 0; nt < 8; ++nt) {
      bfrag B = *(const bfrag*)(frag2 + ((size_t)(ks * 8 + nt) * 64 + lane) * 8);
      acc[0][nt] = __builtin_amdgcn_mfma_f32_16x16x32_bf16(Ab[0], B, acc[0][nt], 0, 0, 0);
      acc[1][nt] = __builtin_amdgcn_mfma_f32_16x16x32_bf16(Ab[1], B, acc[1][nt], 0, 0, 0);
    }
  }

#pragma unroll
  for (int mt = 0; mt < 2; ++mt) {
    int node = nb + mt * 4 + quad;
    if (node < N_NODES) {
      float4 sc0 = {acc[mt][0][0], acc[mt][2][1], acc[mt][2][2], acc[mt][2][3]};
      float4 sc1 = {acc[mt][1][0], acc[mt][3][1], acc[mt][3][2], acc[mt][3][3]};
      float4 x0  = {acc[mt][4][0], acc[mt][6][1], acc[mt][6][2], acc[mt][6][3]};
      float4 x1  = {acc[mt][5][0], acc[mt][7][1], acc[mt][7][2], acc[mt][7][3]};
      ((float4*)out_sc)[(size_t)node * 32 + l16]      = sc0;
      ((float4*)out_sc)[(size_t)node * 32 + 16 + l16] = sc1;
      ((float4*)x_ws)[(size_t)node * 32 + l16]        = x0;
      ((float4*)x_ws)[(size_t)node * 32 + 16 + l16]   = x1;
    }
  }
}

// ---------------- per-edge 4-layer MLP via MFMA -> w (bf16, E x 160) -------
// layer-4 output stored PAIR-PACKED per edge row:
//   bf16 idx 2c+0 = w[p=0][c], 2c+1 = w[p=1][c]      (dword pair {w0,w1})
//   64 + 2c+0 = w[p=2][c], 64+2c+1 = w[p=3][c]       (dword pair {w2,w3})
//   128 + c   = w[p=4][c]
#define MLP_M 128
__global__ __launch_bounds__(256) void k_mlp(const float* __restrict__ ef,
                                             const unsigned short* __restrict__ frag,
                                             unsigned short* __restrict__ w_out,
                                             int E) {
  __shared__ __align__(16) unsigned short H[4][32][168];
  int tid = threadIdx.x;
  int wave = tid >> 6, lane = tid & 63;
  int quad = lane >> 4, l16 = lane & 15;
  int m0 = blockIdx.x * MLP_M + wave * 32;   // wave's first edge row
  unsigned short (*Hw)[168] = H[wave];

  // ---- layer 1: A = edge_feats rows (K=8 zero-padded to 32) ----
  bfrag a1[2];
#pragma unroll
  for (int mt = 0; mt < 2; ++mt) {
    float vals[8] = {0.f, 0.f, 0.f, 0.f, 0.f, 0.f, 0.f, 0.f};
    if (quad == 0) {
      int r = m0 + mt * 16 + l16;
      if (r > E - 1) r = E - 1;
      const float4* p = (const float4*)(ef + (size_t)r * 8);
      float4 u0 = p[0], u1 = p[1];
      vals[0] = u0.x; vals[1] = u0.y; vals[2] = u0.z; vals[3] = u0.w;
      vals[4] = u1.x; vals[5] = u1.y; vals[6] = u1.z; vals[7] = u1.w;
    }
    union { unsigned short s[8]; bfrag v; } pk;
#pragma unroll
    for (int j = 0; j < 8; ++j) pk.s[j] = f2bf(vals[j]);
    a1[mt] = pk.v;
  }
#pragma unroll
  for (int nt = 0; nt < 4; ++nt) {
    const bfrag* bp = (const bfrag*)(frag + ((size_t)(nt) * 64 + lane) * 8);
    bfrag b = *bp;
    ffrag acc0 = {0.f, 0.f, 0.f, 0.f}, acc1 = acc0;
    acc0 = __builtin_amdgcn_mfma_f32_16x16x32_bf16(a1[0], b, acc0, 0, 0, 0);
    acc1 = __builtin_amdgcn_mfma_f32_16x16x32_bf16(a1[1], b, acc1, 0, 0, 0);
#pragma unroll
    for (int r = 0; r < 4; ++r) {
      Hw[0 * 16 + quad * 4 + r][nt * 16 + l16] = f2bf(rsilu(acc0[r]));
      Hw[1 * 16 + quad * 4 + r][nt * 16 + l16] = f2bf(rsilu(acc1[r]));
    }
  }

  // ---- layers 2,3 (N=64) ----
  bfrag A[2][2];
#pragma unroll 1
  for (int L = 0; L < 2; ++L) {           // layers 2 and 3
    int fbase = 4 + L * 8;
#pragma unroll
    for (int mt = 0; mt < 2; ++mt)
#pragma unroll
      for (int ks = 0; ks < 2; ++ks)
        A[mt][ks] = *(const bfrag*)&Hw[mt * 16 + l16][ks * 32 + quad * 8];
#pragma unroll
    for (int nt = 0; nt < 4; ++nt) {
      ffrag acc0 = {0.f, 0.f, 0.f, 0.f}, acc1 = acc0;
#pragma unroll
      for (int ks = 0; ks < 2; ++ks) {
        bfrag b = *(const bfrag*)(frag + ((size_t)(fbase + nt * 2 + ks) * 64 + lane) * 8);
        acc0 = __builtin_amdgcn_mfma_f32_16x16x32_bf16(A[0][ks], b, acc0, 0, 0, 0);
        acc1 = __builtin_amdgcn_mfma_f32_16x16x32_bf16(A[1][ks], b, acc1, 0, 0, 0);
      }
#pragma unroll
      for (int r = 0; r < 4; ++r) {
        Hw[0 * 16 + quad * 4 + r][nt * 16 + l16] = f2bf(rsilu(acc0[r]));
        Hw[1 * 16 + quad * 4 + r][nt * 16 + l16] = f2bf(rsilu(acc1[r]));
      }
    }
  }

  // layer 4: w = h3 @ Wr3^T / 8 (scale pre-folded), no activation;
  // pair-packed column permutation
#pragma unroll
  for (int mt = 0; mt < 2; ++mt)
#pragma unroll
    for (int ks = 0; ks < 2; ++ks)
      A[mt][ks] = *(const bfrag*)&Hw[mt * 16 + l16][ks * 32 + quad * 8];
#pragma unroll 2
  for (int nt = 0; nt < 10; ++nt) {
    ffrag acc0 = {0.f, 0.f, 0.f, 0.f}, acc1 = acc0;
#pragma unroll
    for (int ks = 0; ks < 2; ++ks) {
      bfrag b = *(const bfrag*)(frag + ((size_t)(20 + nt * 2 + ks) * 64 + lane) * 8);
      acc0 = __builtin_amdgcn_mfma_f32_16x16x32_bf16(A[0][ks], b, acc0, 0, 0, 0);
      acc1 = __builtin_amdgcn_mfma_f32_16x16x32_bf16(A[1][ks], b, acc1, 0, 0, 0);
    }
    int col = nt * 16 + l16;
    int p = col >> 5, cc = col & 31;
    int ncol = (p < 4) ? ((p >> 1) * 64 + 2 * cc + (p & 1)) : (128 + cc);
#pragma unroll
    for (int r = 0; r < 4; ++r) {
      Hw[0 * 16 + quad * 4 + r][ncol] = f2bf(acc0[r]);
      Hw[1 * 16 + quad * 4 + r][ncol] = f2bf(acc1[r]);
    }
  }

  // flush: 32 rows x 160 bf16 -> global, 16 B chunks; incremental row/off
  // (c = it*64+lane; 64 = 3*20 + 4)
  {
    int row = lane / 20, off = lane - row * 20;
    int grow_base = m0;
#pragma unroll 2
    for (int it = 0; it < 10; ++it) {
      int grow = grow_base + row;
      uint4 v = *(const uint4*)&Hw[row][off * 8];
      if (grow < E)
        *(uint4*)(w_out + (size_t)grow * 160 + off * 8) = v;
      off += 4;
      row += 3;
      if (off >= 20) { off -= 20; row += 1; }
    }
  }
}

// ---------------- per-node message accumulation + W_second contraction ----------------
// v6:
//  - edge loop unchanged (3 w loads/edge pair-packed, batch 4, no-spill).
//  - tail contraction replaced by per-wave MFMA GEMMs:
//      wave 0: out0 = msg0[8x64] @ Ws0^T[64x32]   (comp 0)
//      wave w=1..3: out1[m=w-1] = msg1_m[8x96] @ Ws1^T[96x32]  (comp w)
//    A-frags from msg LDS (rows clamped &7; dup rows ignored at writeout),
//    B-frags built from Ws0/Ws1 directly from global (L1/L2-resident),
//    output scale folded into B before bf16 quantization.
//  - W LDS staging deleted: LDS 32.5KB -> 11.4KB -> 8 blocks/CU (thread cap).
__global__ __launch_bounds__(256) void k_msg(const unsigned short* __restrict__ w_ws,
                                             const float* __restrict__ x_ws,
                                             const float* __restrict__ ea,
                                             const int* __restrict__ idx_j,
                                             const int* __restrict__ row,
                                             const float* __restrict__ Ws0,
                                             const float* __restrict__ Ws1,
                                             float* __restrict__ out_msg) {
  __shared__ __align__(16) float msg[8][356];  // 352 comps, stride 356 (16B-aligned)

  int tid = threadIdx.x;
  int ln = tid >> 5, c = tid & 31;
  int n = blockIdx.x * 8 + ln;                // grid exactly N/8
  int e0 = row[n], e1 = row[n + 1];

  float m00 = 0.f, m01 = 0.f;
  float m10x = 0.f, m10y = 0.f, m10z = 0.f;
  float m11x = 0.f, m11y = 0.f, m11z = 0.f;
  float m12x = 0.f, m12y = 0.f, m12z = 0.f;

  for (int base = e0; base < e1; base += 32) {
    int rem = e1 - base;
    int cnt = rem < 32 ? rem : 32;
    // one coalesced load covers this chunk's indices (dup-clamped for c>=cnt)
    int jidx = base + (c < cnt ? c : cnt - 1);
    int j_c = __builtin_nontemporal_load(idx_j + jidx);

    for (int b = 0; b < cnt; b += 4) {
      int mvalid = cnt - b;                   // >= 1
      float4 xj[4], y4[4];
      unsigned d01[4], d23[4];
      unsigned short w4v[4];
#pragma unroll
      for (int t = 0; t < 4; ++t) {
        int tt = (t < mvalid) ? t : 0;        // clamp to a valid edge (loads safe)
        int e = base + b + tt;
        int j = __shfl(j_c, b + tt, 32);
        xj[t] = ((const float4*)x_ws)[(size_t)j * 32 + c];
        y4[t] = ((const float4*)ea)[e];
        const char* wb = (const char*)w_ws + (size_t)e * 320;
        d01[t] = *(const unsigned*)(wb + 4 * c);
        d23[t] = *(const unsigned*)(wb + 128 + 4 * c);
        w4v[t] = *(const unsigned short*)(wb + 256 + 2 * c);
      }
#pragma unroll
      for (int t = 0; t < 4; ++t) {
        if (t < mvalid) {
          float w0 = __uint_as_float(d01[t] << 16);
          float w1 = __uint_as_float(d01[t] & 0xffff0000u);
          float w2 = __uint_as_float(d23[t] << 16);
          float w3 = __uint_as_float(d23[t] & 0xffff0000u);
          float w4 = bf2f(w4v[t]);
          float4 x4 = xj[t], yy = y4[t];
          m00 += w0 * x4.x * yy.x;                                      // p0
          m01 += w3 * (x4.y * yy.y + x4.z * yy.z + x4.w * yy.w);        // p3
          m10x += w1 * x4.x * yy.y;
          m10y += w1 * x4.x * yy.z;
          m10z += w1 * x4.x * yy.w;                                     // p1
          m11x += w2 * x4.y * yy.x;
          m11y += w2 * x4.z * yy.x;
          m11z += w2 * x4.w * yy.x;                                     // p2
          float cx = x4.z * yy.w - x4.w * yy.z;
          float cy = x4.w * yy.y - x4.y * yy.w;
          float cz = x4.y * yy.z - x4.z * yy.y;
          m12x += w4 * cx;
          m12y += w4 * cy;
          m12z += w4 * cz;                                              // p4
        }
      }
    }
  }

  // msg row layout: [0..63] = {m00, m01}; [64 + m*96 + p'*32 + c], p' in {p1,p2,p4}
  msg[ln][c]      = m00;
  msg[ln][32 + c] = m01;
  msg[ln][64 + 0 * 96 +  0 + c] = m10x;
  msg[ln][64 + 0 * 96 + 32 + c] = m11x;
  msg[ln][64 + 0 * 96 + 64 + c] = m12x;
  msg[ln][64 + 1 * 96 +  0 + c] = m10y;
  msg[ln][64 + 1 * 96 + 32 + c] = m11y;
  msg[ln][64 + 1 * 96 + 64 + c] = m12y;
  msg[ln][64 + 2 * 96 +  0 + c] = m10z;
  msg[ln][64 + 2 * 96 + 32 + c] = m11z;
  msg[ln][64 + 2 * 96 + 64 + c] = m12z;
  __syncthreads();

  // ---- MFMA tail ----
  int wv = tid >> 6;                 // wave 0..3 -> output comp 0..3
  int lane = tid & 63;
  int quad = lane >> 4, l16 = lane & 15;
  int nb = blockIdx.x * 8;

  const float* WS   = (wv == 0) ? Ws0 : Ws1;
  int   K      = (wv == 0) ? 64 : 96;
  int   mbase  = (wv == 0) ? 0 : 64 + (wv - 1) * 96;
  float oscale = (wv == 0) ? (INV8 * INV_AVG) : (INV_SQRT96 * INV_AVG);

  ffrag acc0 = {0.f, 0.f, 0.f, 0.f}, acc1 = acc0;
  const float* arow = &msg[l16 & 7][mbase + quad * 8];   // rows 8-15 dup rows 0-7
#pragma unroll 1
  for (int ks = 0; ks < K; ks += 32) {
    float4 a0 = *(const float4*)(arow + ks);
    float4 a1 = *(const float4*)(arow + ks + 4);
    union { unsigned short s[8]; bfrag v; } pa;
    pa.s[0] = f2bf(a0.x); pa.s[1] = f2bf(a0.y); pa.s[2] = f2bf(a0.z); pa.s[3] = f2bf(a0.w);
    pa.s[4] = f2bf(a1.x); pa.s[5] = f2bf(a1.y); pa.s[6] = f2bf(a1.z); pa.s[7] = f2bf(a1.w);

    const float* bp0 = WS + (size_t)l16 * K + ks + quad * 8;
    const float* bp1 = bp0 + (size_t)16 * K;
    {
      float4 b0 = *(const float4*)(bp0);
      float4 b1 = *(const float4*)(bp0 + 4);
      union { unsigned short s[8]; bfrag v; } pb;
      pb.s[0] = f2bf(b0.x * oscale); pb.s[1] = f2bf(b0.y * oscale);
      pb.s[2] = f2bf(b0.z * oscale); pb.s[3] = f2bf(b0.w * oscale);
      pb.s[4] = f2bf(b1.x * oscale); pb.s[5] = f2bf(b1.y * oscale);
      pb.s[6] = f2bf(b1.z * oscale); pb.s[7] = f2bf(b1.w * oscale);
      acc0 = __builtin_amdgcn_mfma_f32_16x16x32_bf16(pa.v, pb.v, acc0, 0, 0, 0);
    }
    {
      float4 b0 = *(const float4*)(bp1);
      float4 b1 = *(const float4*)(bp1 + 4);
      union { unsigned short s[8]; bfrag v; } pb;
      pb.s[0] = f2bf(b0.x * oscale); pb.s[1] = f2bf(b0.y * oscale);
      pb.s[2] = f2bf(b0.z * oscale); pb.s[3] = f2bf(b0.w * oscale);
      pb.s[4] = f2bf(b1.x * oscale); pb.s[5] = f2bf(b1.y * oscale);
      pb.s[6] = f2bf(b1.z * oscale); pb.s[7] = f2bf(b1.w * oscale);
      acc1 = __builtin_amdgcn_mfma_f32_16x16x32_bf16(pa.v, pb.v, acc1, 0, 0, 0);
    }
  }

  // C/D: row = quad*4 + r (node, valid < 8), col = l16 (d within tile)
#pragma unroll
  for (int r = 0; r < 4; ++r) {
    int rowv = quad * 4 + r;
    if (rowv < 8) {
      size_t base = (size_t)(nb + rowv) * 128 + (size_t)l16 * 4 + wv;
      out_msg[base]      = acc0[r];        // d = l16
      out_msg[base + 64] = acc1[r];        // d = 16 + l16
    }
  }
}

extern "C" void kernel_launch(void* const* d_in, const int* in_sizes, int n_in,
                              void* d_out, int out_size, void* d_ws, size_t ws_size,
                              hipStream_t stream) {
  const float* node_attrs = (const float*)d_in[0];
  const float* node_feats = (const float*)d_in[1];
  const float* edge_attrs = (const float*)d_in[2];
  const float* edge_feats = (const float*)d_in[3];
  const float* W_first    = (const float*)d_in[4];
  const float* Wr0        = (const float*)d_in[5];
  const float* Wr1        = (const float*)d_in[6];
  const float* Wr2        = (const float*)d_in[7];
  const float* Wr3        = (const float*)d_in[8];
  const float* Ws0        = (const float*)d_in[9];
  const float* Ws1        = (const float*)d_in[10];
  const float* Wsk        = (const float*)d_in[11];
  const int*   idx_i      = (const int*)d_in[12];
  const int*   idx_j      = (const int*)d_in[13];
  float* out = (float*)d_out;

  char* ws = (char*)d_ws;
  float*          x_ws   = (float*)(ws + OFF_X);
  int*            rowp   = (int*)(ws + OFF_ROW);
  unsigned short* fragp  = (unsigned short*)(ws + OFF_FRAG);
  unsigned short* frag2p = (unsigned short*)(ws + OFF_FRAG2);
  unsigned short* w_ws   = (unsigned short*)(ws + OFF_W);

  k_rowstart<<<(N_EDGES + 255) / 256, 256, 0, stream>>>(idx_i, rowp, N_EDGES, N_NODES);
  k_prep<<<80, 256, 0, stream>>>(Wr0, Wr1, Wr2, Wr3, fragp);
  k_prep2<<<176, 256, 0, stream>>>(Wsk, W_first, frag2p);
  k_node_mfma<<<(N_NODES + 31) / 32, 256, 0, stream>>>(node_attrs, node_feats,
                                                       frag2p, out + 6400000, x_ws);
  k_mlp<<<(N_EDGES + MLP_M - 1) / MLP_M, 256, 0, stream>>>(edge_feats, fragp,
                                                           w_ws, N_EDGES);
  k_msg<<<N_NODES / 8, 256, 0, stream>>>(w_ws, x_ws, edge_attrs, idx_j, rowp,
                                         Ws0, Ws1, out);
}